// Round 1
// baseline (7100.494 us; speedup 1.0000x reference)
//
#include <hip/hip_runtime.h>
#include <cstddef>

#define LN_EPS 1e-6f
#define NEG_SLOPE 0.2f

// ---------------------------------------------------------------------------
// Generic init: zero a big region, set m=-1e30 and s=0 for softmax state
// ---------------------------------------------------------------------------
__global__ void init_zero_minf(float* __restrict__ zbuf, size_t nz,
                               float* __restrict__ m, float* __restrict__ s, int nm)
{
    size_t tid = (size_t)blockIdx.x * blockDim.x + threadIdx.x;
    size_t stride = (size_t)gridDim.x * blockDim.x;
    for (size_t i = tid; i < nz; i += stride) zbuf[i] = 0.0f;
    for (size_t i = tid; i < (size_t)nm; i += stride) { m[i] = -1e30f; s[i] = 0.0f; }
}

// ---------------------------------------------------------------------------
// fp32 tiled GEMM: C[M,Nc] = op(A)[M,K] @ B[K,Nc]
// op(A) = relu(A + bias[k]) when applyReluBias, else A. A has row stride lda.
// BM=64, BN=64, BK=16, 256 threads, 4x4 microtile.
// ---------------------------------------------------------------------------
__global__ __launch_bounds__(256)
void gemm_f32(const float* __restrict__ A, long lda,
              const float* __restrict__ B,
              const float* __restrict__ bias, int applyReluBias,
              float* __restrict__ C, int M, int Nc, int K)
{
    __shared__ float As[16][68];   // [k][m], +4 pad keeps 16B alignment for b128 reads
    __shared__ float Bs[16][68];   // [k][n]

    const int t  = threadIdx.x;
    const int tx = t & 15, ty = t >> 4;
    const int mb = blockIdx.y * 64;
    const int nb = blockIdx.x * 64;

    const int arow = t >> 2;          // 0..63
    const int akq  = (t & 3) * 4;     // 0,4,8,12
    const int brow = t >> 4;          // 0..15
    const int bcq  = (t & 15) * 4;    // 0..60

    float acc[4][4] = {};

    for (int kb = 0; kb < K; kb += 16) {
        float4 av = make_float4(0.f, 0.f, 0.f, 0.f);
        int gm = mb + arow;
        if (gm < M) av = *(const float4*)(A + (size_t)gm * lda + kb + akq);
        if (applyReluBias) {
            av.x = fmaxf(av.x + bias[kb + akq + 0], 0.f);
            av.y = fmaxf(av.y + bias[kb + akq + 1], 0.f);
            av.z = fmaxf(av.z + bias[kb + akq + 2], 0.f);
            av.w = fmaxf(av.w + bias[kb + akq + 3], 0.f);
        }
        As[akq + 0][arow] = av.x;
        As[akq + 1][arow] = av.y;
        As[akq + 2][arow] = av.z;
        As[akq + 3][arow] = av.w;

        float4 bv = *(const float4*)(B + (size_t)(kb + brow) * Nc + nb + bcq);
        *(float4*)&Bs[brow][bcq] = bv;

        __syncthreads();
#pragma unroll
        for (int k = 0; k < 16; ++k) {
            float4 a4 = *(const float4*)&As[k][ty * 4];
            float4 b4 = *(const float4*)&Bs[k][tx * 4];
            acc[0][0] += a4.x * b4.x; acc[0][1] += a4.x * b4.y; acc[0][2] += a4.x * b4.z; acc[0][3] += a4.x * b4.w;
            acc[1][0] += a4.y * b4.x; acc[1][1] += a4.y * b4.y; acc[1][2] += a4.y * b4.z; acc[1][3] += a4.y * b4.w;
            acc[2][0] += a4.z * b4.x; acc[2][1] += a4.z * b4.y; acc[2][2] += a4.z * b4.z; acc[2][3] += a4.z * b4.w;
            acc[3][0] += a4.w * b4.x; acc[3][1] += a4.w * b4.y; acc[3][2] += a4.w * b4.z; acc[3][3] += a4.w * b4.w;
        }
        __syncthreads();
    }

#pragma unroll
    for (int i = 0; i < 4; ++i) {
        int gm = mb + ty * 4 + i;
        if (gm < M) {
            float4 o = make_float4(acc[i][0], acc[i][1], acc[i][2], acc[i][3]);
            *(float4*)(C + (size_t)gm * Nc + nb + tx * 4) = o;
        }
    }
}

// ---------------------------------------------------------------------------
// a_src[w] = dot(h[w,:256], att_src[w%heads,:]), a_dst likewise. One wave/row.
// ---------------------------------------------------------------------------
__global__ void att_dots(const float* __restrict__ h,
                         const float* __restrict__ att_s, const float* __restrict__ att_d,
                         float* __restrict__ a_s, float* __restrict__ a_d,
                         int NH, int heads)
{
    int w = blockIdx.x * (blockDim.x >> 6) + (threadIdx.x >> 6);
    if (w >= NH) return;
    int lane = threadIdx.x & 63;
    int hh = w % heads;
    const float4 hv = *(const float4*)(h + (size_t)w * 256 + lane * 4);
    const float4 sv = *(const float4*)(att_s + (size_t)hh * 256 + lane * 4);
    const float4 dv = *(const float4*)(att_d + (size_t)hh * 256 + lane * 4);
    float ss = hv.x * sv.x + hv.y * sv.y + hv.z * sv.z + hv.w * sv.w;
    float sd = hv.x * dv.x + hv.y * dv.y + hv.z * dv.z + hv.w * dv.w;
#pragma unroll
    for (int off = 32; off; off >>= 1) {
        ss += __shfl_xor(ss, off);
        sd += __shfl_xor(sd, off);
    }
    if (lane == 0) { a_s[w] = ss; a_d[w] = sd; }
}

// ---------------------------------------------------------------------------
// Edge softmax pass 1: m[dst,h] = max over edges of leaky_relu(a_s[src]+a_d[dst])
// float atomic max via int/uint ordering trick.
// ---------------------------------------------------------------------------
__global__ void edge_max(const int* __restrict__ ei, int E, int N, int heads,
                         const float* __restrict__ a_s, const float* __restrict__ a_d,
                         float* __restrict__ m)
{
    int e = blockIdx.x * blockDim.x + threadIdx.x;
    if (e >= E + N) return;
    int src = (e < E) ? ei[e]     : (e - E);
    int dst = (e < E) ? ei[E + e] : (e - E);
    for (int h = 0; h < heads; ++h) {
        float el = a_s[src * heads + h] + a_d[dst * heads + h];
        el = (el > 0.f) ? el : NEG_SLOPE * el;
        float* addr = &m[dst * heads + h];
        if (el >= 0.f) atomicMax((int*)addr, __float_as_int(el));
        else           atomicMin((unsigned int*)addr, (unsigned int)__float_as_int(el));
    }
}

// ---------------------------------------------------------------------------
// Edge softmax pass 2: ex = exp(e - m[dst]); s[dst] += ex; store ex per edge.
// ---------------------------------------------------------------------------
__global__ void edge_sum(const int* __restrict__ ei, int E, int N, int heads,
                         const float* __restrict__ a_s, const float* __restrict__ a_d,
                         const float* __restrict__ m, float* __restrict__ s,
                         float* __restrict__ exbuf)
{
    int e = blockIdx.x * blockDim.x + threadIdx.x;
    if (e >= E + N) return;
    int src = (e < E) ? ei[e]     : (e - E);
    int dst = (e < E) ? ei[E + e] : (e - E);
    for (int h = 0; h < heads; ++h) {
        float el = a_s[src * heads + h] + a_d[dst * heads + h];
        el = (el > 0.f) ? el : NEG_SLOPE * el;
        float ex = expf(el - m[dst * heads + h]);
        exbuf[(size_t)e * heads + h] = ex;
        unsafeAtomicAdd(&s[dst * heads + h], ex);
    }
}

// ---------------------------------------------------------------------------
// Edge aggregation: agg[dst, :] += alpha * h[src, :]. One block per edge,
// blockDim = heads*256/4 threads (float4 each). Optionally emits alpha.
// ---------------------------------------------------------------------------
__global__ void edge_aggr(const int* __restrict__ ei, int E, int N, int heads,
                          const float* __restrict__ ex, const float* __restrict__ s,
                          const float* __restrict__ h, float* __restrict__ agg,
                          float* __restrict__ alpha_out)
{
    int e = blockIdx.x;
    int src = (e < E) ? ei[e]     : (e - E);
    int dst = (e < E) ? ei[E + e] : (e - E);
    int t = threadIdx.x;
    int c0 = t * 4;
    int hh = c0 >> 8;
    int F = blockDim.x * 4;          // heads*256
    float alpha = ex[(size_t)e * heads + hh] / s[dst * heads + hh];
    if (alpha_out != nullptr && t == 0) alpha_out[e] = alpha;
    const float4 hv = *(const float4*)(h + (size_t)src * F + c0);
    float* ap = agg + (size_t)dst * F + c0;
    unsafeAtomicAdd(ap + 0, alpha * hv.x);
    unsafeAtomicAdd(ap + 1, alpha * hv.y);
    unsafeAtomicAdd(ap + 2, alpha * hv.z);
    unsafeAtomicAdd(ap + 3, alpha * hv.w);
}

// ---------------------------------------------------------------------------
// Final: y = x + g2[n] + bias2 ; out = lnw * y * rsqrt(mean(y^2) + eps)
// One wave per (n,s) row of 256.
// ---------------------------------------------------------------------------
__global__ void ln_final(const float* __restrict__ x, const float* __restrict__ g2,
                         const float* __restrict__ b2, const float* __restrict__ lnw,
                         float* __restrict__ out, int rows, int S)
{
    int w = blockIdx.x * (blockDim.x >> 6) + (threadIdx.x >> 6);
    if (w >= rows) return;
    int lane = threadIdx.x & 63;
    int n = w / S;
    size_t base = (size_t)w * 256 + lane * 4;
    float4 xv = *(const float4*)(x + base);
    float4 gv = *(const float4*)(g2 + (size_t)n * 256 + lane * 4);
    float4 bv = *(const float4*)(b2 + lane * 4);
    float4 y;
    y.x = xv.x + gv.x + bv.x;
    y.y = xv.y + gv.y + bv.y;
    y.z = xv.z + gv.z + bv.z;
    y.w = xv.w + gv.w + bv.w;
    float ss = y.x * y.x + y.y * y.y + y.z * y.z + y.w * y.w;
#pragma unroll
    for (int off = 32; off; off >>= 1) ss += __shfl_xor(ss, off);
    float r = rsqrtf(ss * (1.0f / 256.0f) + LN_EPS);
    float4 wv = *(const float4*)(lnw + lane * 4);
    float4 o;
    o.x = wv.x * y.x * r;
    o.y = wv.y * y.y * r;
    o.z = wv.z * y.z * r;
    o.w = wv.w * y.w * r;
    *(float4*)(out + base) = o;
}

// ---------------------------------------------------------------------------
extern "C" void kernel_launch(void* const* d_in, const int* in_sizes, int n_in,
                              void* d_out, int out_size, void* d_ws, size_t ws_size,
                              hipStream_t stream)
{
    const float* x   = (const float*)d_in[0];
    const int*   ei  = (const int*)  d_in[1];
    const float* W1  = (const float*)d_in[2];
    const float* as1 = (const float*)d_in[3];
    const float* ad1 = (const float*)d_in[4];
    const float* b1  = (const float*)d_in[5];
    const float* W2  = (const float*)d_in[6];
    const float* as2 = (const float*)d_in[7];
    const float* ad2 = (const float*)d_in[8];
    const float* b2  = (const float*)d_in[9];
    const float* lnw = (const float*)d_in[10];

    const int H = 256, S = 32, heads = 4;
    const int N  = in_sizes[0] / (S * H);     // 20000
    const int E  = in_sizes[1] / 2;           // 320000
    const int Et = E + N;                     // 340000
    const int F1 = heads * H;                 // 1024

    // workspace layout (floats); h1 region reused for h2+agg2 after L1 aggr
    float* ws = (float*)d_ws;
    size_t off = 0;
    float* agg1 = ws + off; off += (size_t)N * F1;   // 20.48M
    float* h1   = ws + off; off += (size_t)N * F1;   // 20.48M
    float* h2   = h1;                                 // overlay (h1 dead after aggr1)
    float* agg2 = h1 + (size_t)N * H;                 // overlay
    float* a_s1 = ws + off; off += (size_t)N * heads;
    float* a_d1 = ws + off; off += (size_t)N * heads;
    float* m1   = ws + off; off += (size_t)N * heads;
    float* s1   = ws + off; off += (size_t)N * heads;
    float* a_s2 = ws + off; off += N;
    float* a_d2 = ws + off; off += N;
    float* m2   = ws + off; off += N;
    float* s2   = ws + off; off += N;
    float* ex1  = ws + off; off += (size_t)Et * heads;
    float* ex2  = ex1;                                // reuse (ex1 dead after aggr1)

    float* out       = (float*)d_out;
    float* alpha_out = out + (size_t)N * S * H;

    // ---- Layer 1 ----
    init_zero_minf<<<2048, 256, 0, stream>>>(agg1, (size_t)N * F1, m1, s1, N * heads);

    dim3 g1grid(F1 / 64, (N + 63) / 64);
    gemm_f32<<<g1grid, 256, 0, stream>>>(x, (long)S * H, W1, nullptr, 0, h1, N, F1, H);

    att_dots<<<(N * heads + 3) / 4, 256, 0, stream>>>(h1, as1, ad1, a_s1, a_d1, N * heads, heads);

    int eb = (Et + 255) / 256;
    edge_max<<<eb, 256, 0, stream>>>(ei, E, N, heads, a_s1, a_d1, m1);
    edge_sum<<<eb, 256, 0, stream>>>(ei, E, N, heads, a_s1, a_d1, m1, s1, ex1);
    edge_aggr<<<Et, 256, 0, stream>>>(ei, E, N, heads, ex1, s1, h1, agg1, nullptr);

    // ---- Layer 2 ----
    init_zero_minf<<<512, 256, 0, stream>>>(agg2, (size_t)N * H, m2, s2, N);

    dim3 g2grid(H / 64, (N + 63) / 64);
    gemm_f32<<<g2grid, 256, 0, stream>>>(agg1, (long)F1, W2, b1, 1, h2, N, H, F1);

    att_dots<<<(N + 3) / 4, 256, 0, stream>>>(h2, as2, ad2, a_s2, a_d2, N, 1);

    edge_max<<<eb, 256, 0, stream>>>(ei, E, N, 1, a_s2, a_d2, m2);
    edge_sum<<<eb, 256, 0, stream>>>(ei, E, N, 1, a_s2, a_d2, m2, s2, ex2);
    edge_aggr<<<Et, 64, 0, stream>>>(ei, E, N, 1, ex2, s2, h2, agg2, alpha_out);

    // ---- Residual + layernorm ----
    ln_final<<<(N * S + 3) / 4, 256, 0, stream>>>(x, agg2, b2, lnw, out, N * S, S);
}